// Round 14
// baseline (149.504 us; speedup 1.0000x reference)
//
#include <hip/hip_runtime.h>

#define NEG_SLOPE 0.2f
#define LRELU(x) ((x) > 0.0f ? (x) : NEG_SLOPE * (x))

typedef short short8 __attribute__((ext_vector_type(8)));
typedef unsigned short ushort8 __attribute__((ext_vector_type(8)));
typedef float f32x4v __attribute__((ext_vector_type(4)));

__device__ __forceinline__ unsigned short f2bf(float f) {
  unsigned int u = __float_as_uint(f);
  unsigned int r = (u + 0x7FFFu + ((u >> 16) & 1u)) >> 16;
  return (unsigned short)r;
}

__device__ __forceinline__ float bf2f(unsigned short u) {
  return __uint_as_float(((unsigned int)u) << 16);
}

__device__ __forceinline__ unsigned int cvt_pk_bf16(float lo, float hi) {
  unsigned int r;
  asm("v_cvt_pk_bf16_f32 %0, %1, %2" : "=v"(r) : "v"(lo), "v"(hi));
  return r;
}

__device__ __forceinline__ void gload_lds16(const void* g, void* l) {
  __builtin_amdgcn_global_load_lds(
      (const __attribute__((address_space(1))) unsigned int*)g,
      (__attribute__((address_space(3))) unsigned int*)l, 16, 0, 0);
}

// block-range split constants
#define CBC 448    // count blocks (fused_cg, scheduled first)
#define CBF 1024   // fill blocks

// ---- K1: convert_wt || zero deg || zero gtotal ------------------------------
__global__ __launch_bounds__(256) void prep_kernel(
    const float* __restrict__ W, unsigned short* __restrict__ Wtb,
    int* __restrict__ deg, int* __restrict__ gtotal, int N) {
  int t = blockIdx.x * 256 + threadIdx.x;  // 0..16383
  for (int idx = t; idx < 256 * 256; idx += 64 * 256) {
    int n = idx >> 8, k = idx & 255;
    Wtb[n * 256 + k] = f2bf(W[k * 256 + n]);
  }
  for (int i = t; i < N; i += 64 * 256) deg[i] = 0;
  if (t == 0) *gtotal = 0;
}

// ---- K2: count+rank (blocks [0,CBC)) || MFMA GEMM ---------------------------
// count: rank[e] = old deg value (coalesced store) -> fill needs NO atomics.
// gemm: 128x128 tile, reg-staged f32 A -> cvt_pk -> bf16 LDS; B via gload_lds;
// XCD-paired mapping (m-block count % 8 == 0 via Mp padded to 1024 rows).
__global__ __launch_bounds__(256) void fused_cg(
    const float* __restrict__ Xf, const unsigned short* __restrict__ Wtb,
    const float* __restrict__ attS, const float* __restrict__ attD,
    unsigned short* __restrict__ XHb, float* __restrict__ a_src,
    float* __restrict__ a_dst,
    const int* __restrict__ ei, int* __restrict__ deg,
    int* __restrict__ rank, int E, int N) {
  __shared__ unsigned short lA[128 * 32];  // 8KB [row][k], 64B/row
  __shared__ unsigned short lB[128 * 32];  // 8KB [n][k],   64B/row
  const int bid = blockIdx.x;
  const int tid = threadIdx.x;

  if (bid < CBC) {
    // ---------------- count + rank ----------------
    for (int e = bid * 256 + tid; e < E; e += CBC * 256)
      rank[e] = atomicAdd(&deg[ei[E + e]], 1);
    return;
  }

  // ---------------- gemm ----------------
  const int gb = bid - CBC;
  const int lane = tid & 63;
  const int wave = tid >> 6;
  const int m0 = ((gb >> 4) * 8 + (gb & 7)) * 128;
  const int n0 = ((gb >> 3) & 1) * 128;
  const int wr = (wave >> 1) * 64;
  const int wc = (wave & 1) * 64;

  f32x4v acc[4][4];
#pragma unroll
  for (int i = 0; i < 4; ++i)
#pragma unroll
    for (int j = 0; j < 4; ++j) acc[i][j] = (f32x4v)(0.0f);

  const int srow = tid >> 2;
  const int skb = (tid & 3) * 16;
  const float* ap0 = Xf + (size_t)min(m0 + (tid >> 2), N - 1) * 256 + (tid & 3) * 8;
  const float* ap1 = Xf + (size_t)min(m0 + 64 + (tid >> 2), N - 1) * 256 + (tid & 3) * 8;

  const char* WtC = (const char*)Wtb;
  char* lAc = (char*)&lA[0];
  char* lBc = (char*)&lB[0];
  const int ldsB0 = wave * 1024;
  const int lr = lane & 15;
  const int hq = lane >> 4;
  const int kq = hq * 16;

  float4 c0 = *reinterpret_cast<const float4*>(ap0);
  float4 c1 = *reinterpret_cast<const float4*>(ap0 + 4);
  float4 c2 = *reinterpret_cast<const float4*>(ap1);
  float4 c3 = *reinterpret_cast<const float4*>(ap1 + 4);

#pragma unroll
  for (int kk = 0; kk < 8; ++kk) {
    const int k0 = kk * 32;
    gload_lds16(WtC + (size_t)(n0 + srow) * 512 + (size_t)k0 * 2 + skb, lBc + ldsB0);
    gload_lds16(WtC + (size_t)(n0 + srow + 64) * 512 + (size_t)k0 * 2 + skb,
                lBc + ldsB0 + 4096);
    {
      uint4 w0, w1;
      w0.x = cvt_pk_bf16(c0.x, c0.y); w0.y = cvt_pk_bf16(c0.z, c0.w);
      w0.z = cvt_pk_bf16(c1.x, c1.y); w0.w = cvt_pk_bf16(c1.z, c1.w);
      w1.x = cvt_pk_bf16(c2.x, c2.y); w1.y = cvt_pk_bf16(c2.z, c2.w);
      w1.z = cvt_pk_bf16(c3.x, c3.y); w1.w = cvt_pk_bf16(c3.z, c3.w);
      *reinterpret_cast<uint4*>(lAc + tid * 16) = w0;          // rows 0..63
      *reinterpret_cast<uint4*>(lAc + 4096 + tid * 16) = w1;   // rows 64..127
    }
    if (kk < 7) {
      c0 = *reinterpret_cast<const float4*>(ap0 + k0 + 32);
      c1 = *reinterpret_cast<const float4*>(ap0 + k0 + 36);
      c2 = *reinterpret_cast<const float4*>(ap1 + k0 + 32);
      c3 = *reinterpret_cast<const float4*>(ap1 + k0 + 36);
    }
    __syncthreads();

    short8 a[4], b[4];
#pragma unroll
    for (int i = 0; i < 4; ++i)
      a[i] = *reinterpret_cast<const short8*>(lAc + (wr + i * 16 + lr) * 64 + kq);
#pragma unroll
    for (int j = 0; j < 4; ++j)
      b[j] = *reinterpret_cast<const short8*>(lBc + (wc + j * 16 + lr) * 64 + kq);
#pragma unroll
    for (int i = 0; i < 4; ++i)
#pragma unroll
      for (int j = 0; j < 4; ++j)
        acc[i][j] = __builtin_amdgcn_mfma_f32_16x16x32_bf16(a[i], b[j], acc[i][j], 0, 0, 0);
    __syncthreads();
  }

  // ---- epilogue: fused attention dots + bf16 store ----
  const int h = (n0 + wc) >> 6;
  float ws_[4], wd_[4];
#pragma unroll
  for (int j = 0; j < 4; ++j) {
    ws_[j] = attS[h * 64 + j * 16 + lr];
    wd_[j] = attD[h * 64 + j * 16 + lr];
  }
  const int rbase = m0 + wr + hq * 4;

#pragma unroll
  for (int i = 0; i < 4; ++i) {
#pragma unroll
    for (int r = 0; r < 4; ++r) {
      float ps = 0.f, pd = 0.f;
#pragma unroll
      for (int j = 0; j < 4; ++j) {
        ps += acc[i][j][r] * ws_[j];
        pd += acc[i][j][r] * wd_[j];
      }
#pragma unroll
      for (int off = 1; off < 16; off <<= 1) {
        ps += __shfl_xor(ps, off, 64);
        pd += __shfl_xor(pd, off, 64);
      }
      int row = rbase + i * 16 + r;
      if (lr == 0 && row < N) {
        a_src[row * 4 + h] = ps;
        a_dst[row * 4 + h] = pd;
      }
    }
  }

#pragma unroll
  for (int i = 0; i < 4; ++i)
#pragma unroll
    for (int j = 0; j < 4; ++j) {
      int col = n0 + wc + j * 16 + lr;
#pragma unroll
      for (int r = 0; r < 4; ++r)
        XHb[(size_t)(rbase + i * 16 + r) * 256 + col] = f2bf(acc[i][j][r]);
    }
}

// ---- K3: single-kernel scan, arrival-order region allocation ----------------
// Each block: local exclusive prefix of its deg chunk; leader atomically grabs
// the block's region from gtotal. row_start is NOT globally monotone — valid
// because fill uses row_start[d]+rank[e] and gat_agg uses end = start+deg[d].
__global__ __launch_bounds__(1024) void scan_alloc(const int* __restrict__ deg,
                                                   int* __restrict__ row_start,
                                                   int* __restrict__ gtotal, int N) {
  __shared__ int buf[1024];
  __shared__ int s_off;
  int i = blockIdx.x * 1024 + (int)threadIdx.x;
  int v = (i < N) ? deg[i] : 0;
  buf[threadIdx.x] = v;
  __syncthreads();
  int run = v;
  for (int off = 1; off < 1024; off <<= 1) {
    int t = ((int)threadIdx.x >= off) ? buf[threadIdx.x - off] : 0;
    __syncthreads();
    run += t;
    buf[threadIdx.x] = run;
    __syncthreads();
  }
  if (threadIdx.x == 1023) s_off = atomicAdd(gtotal, run);
  __syncthreads();
  if (i < N) row_start[i] = s_off + run - v;
}

// ---- K4: CSR fill, atomic-free ----------------------------------------------
__global__ __launch_bounds__(256) void fill_kernel(
    const int* __restrict__ ei, const int* __restrict__ row_start,
    const int* __restrict__ rank, int* __restrict__ csr_src, int E) {
  for (int e = blockIdx.x * 256 + threadIdx.x; e < E; e += CBF * 256)
    csr_src[row_start[ei[E + e]] + rank[e]] = ei[e];
}

// ---- K5: fused softmax + aggregation, half-wave row gathers -----------------
// end = start + deg[node] (row_start is per-node region base, not monotone)
__global__ __launch_bounds__(256) void gat_agg(
    const unsigned short* __restrict__ XHb, const float* __restrict__ a_src,
    const float* __restrict__ a_dst, const int* __restrict__ row_start,
    const int* __restrict__ deg, const int* __restrict__ csr_src,
    const float* __restrict__ bias, float* __restrict__ out, int N) {
  int wid = threadIdx.x >> 6;
  int lane = threadIdx.x & 63;
  int node = blockIdx.x * 4 + wid;
  if (node >= N) return;

  const int half = lane >> 5;
  const int l5 = lane & 31;
  const int h = l5 >> 3;
  const int c = l5 << 3;
  const unsigned short* __restrict__ xrow = XHb + c;

  float ad_h = a_dst[node * 4 + h];
  float as_h = a_src[node * 4 + h];

  int start = row_start[node];
  int end = start + deg[node];

  float acc[8];
  float sw = 0.f;
  if (half == 0) {
    float wself = __expf(LRELU(as_h + ad_h));
    ushort8 sv = *reinterpret_cast<const ushort8*>(xrow + (size_t)node * 256);
#pragma unroll
    for (int k = 0; k < 8; ++k) acc[k] = wself * bf2f(sv[k]);
    sw = wself;
  } else {
#pragma unroll
    for (int k = 0; k < 8; ++k) acc[k] = 0.f;
  }

  int p = start;
  for (; p + 8 <= end; p += 8) {
    int s0 = csr_src[p + half];
    int s1 = csr_src[p + 2 + half];
    int s2 = csr_src[p + 4 + half];
    int s3 = csr_src[p + 6 + half];
    float a0 = a_src[s0 * 4 + h] + ad_h;
    float a1 = a_src[s1 * 4 + h] + ad_h;
    float a2 = a_src[s2 * 4 + h] + ad_h;
    float a3 = a_src[s3 * 4 + h] + ad_h;
    ushort8 u0 = *reinterpret_cast<const ushort8*>(xrow + (size_t)s0 * 256);
    ushort8 u1 = *reinterpret_cast<const ushort8*>(xrow + (size_t)s1 * 256);
    ushort8 u2 = *reinterpret_cast<const ushort8*>(xrow + (size_t)s2 * 256);
    ushort8 u3 = *reinterpret_cast<const ushort8*>(xrow + (size_t)s3 * 256);
    float w0 = __expf(LRELU(a0));
    float w1 = __expf(LRELU(a1));
    float w2 = __expf(LRELU(a2));
    float w3 = __expf(LRELU(a3));
#pragma unroll
    for (int k = 0; k < 8; ++k) {
      acc[k] += w0 * bf2f(u0[k]);
      acc[k] += w1 * bf2f(u1[k]);
      acc[k] += w2 * bf2f(u2[k]);
      acc[k] += w3 * bf2f(u3[k]);
    }
    sw += (w0 + w1) + (w2 + w3);
  }
#pragma unroll
  for (int k = 0; k < 4; ++k) {
    int idx = p + 2 * k + half;
    if (idx < end) {
      int s = csr_src[idx];
      float aa = a_src[s * 4 + h] + ad_h;
      ushort8 u = *reinterpret_cast<const ushort8*>(xrow + (size_t)s * 256);
      float ww = __expf(LRELU(aa));
#pragma unroll
      for (int q = 0; q < 8; ++q) acc[q] += ww * bf2f(u[q]);
      sw += ww;
    }
  }

  sw += __shfl_xor(sw, 32, 64);
#pragma unroll
  for (int k = 0; k < 8; ++k) acc[k] += __shfl_xor(acc[k], 32, 64);

  if (half == 0) {
    float inv = 1.0f / sw;
    float4 b0 = *reinterpret_cast<const float4*>(bias + c);
    float4 b1 = *reinterpret_cast<const float4*>(bias + c + 4);
    float4 o0, o1;
    o0.x = acc[0] * inv + b0.x; o0.y = acc[1] * inv + b0.y;
    o0.z = acc[2] * inv + b0.z; o0.w = acc[3] * inv + b0.w;
    o1.x = acc[4] * inv + b1.x; o1.y = acc[5] * inv + b1.y;
    o1.z = acc[6] * inv + b1.z; o1.w = acc[7] * inv + b1.w;
    *reinterpret_cast<float4*>(out + (size_t)node * 256 + c) = o0;
    *reinterpret_cast<float4*>(out + (size_t)node * 256 + c + 4) = o1;
  }
}

extern "C" void kernel_launch(void* const* d_in, const int* in_sizes, int n_in,
                              void* d_out, int out_size, void* d_ws, size_t ws_size,
                              hipStream_t stream) {
  const float* x    = (const float*)d_in[0];
  const int*   ei   = (const int*)d_in[1];
  const float* Wm   = (const float*)d_in[2];
  const float* attS = (const float*)d_in[3];
  const float* attD = (const float*)d_in[4];
  const float* bias = (const float*)d_in[5];
  float* out = (float*)d_out;

  const int N = in_sizes[0] / 256;
  const int E = in_sizes[1] / 2;
  // m-block count must be a multiple of 8 for the XCD-paired gemm mapping
  const int Mp = (N + 1023) / 1024 * 1024;
  const int nb = (N + 1023) / 1024;

  char* w = (char*)d_ws;
  unsigned short* XHb = (unsigned short*)w;  w += (size_t)Mp * 256 * 2;
  unsigned short* Wtb = (unsigned short*)w;  w += (size_t)256 * 256 * 2;
  float* a_src = (float*)w;                  w += (size_t)N * 4 * 4;
  float* a_dst = (float*)w;                  w += (size_t)N * 4 * 4;
  int* deg = (int*)w;                        w += (size_t)N * 4;
  int* rank = (int*)w;                       w += (size_t)E * 4;
  int* row_start = (int*)w;                  w += ((size_t)(N + 1) * 4 + 255) / 256 * 256;
  int* gtotal = (int*)w;                     w += 256;
  int* csr_src = (int*)w;                    w += (size_t)E * 4;

  // K1: convert W || zero deg || zero gtotal
  prep_kernel<<<64, 256, 0, stream>>>(Wm, Wtb, deg, gtotal, N);

  // K2: count+rank || gemm (count hides under gemm)
  const int nGemm = 2 * (Mp / 128);
  fused_cg<<<CBC + nGemm, 256, 0, stream>>>(x, Wtb, attS, attD, XHb, a_src, a_dst,
                                            ei, deg, rank, E, N);

  // K3: single-kernel scan (arrival-order region allocation)
  scan_alloc<<<nb, 1024, 0, stream>>>(deg, row_start, gtotal, N);

  // K4: atomic-free fill
  fill_kernel<<<CBF, 256, 0, stream>>>(ei, row_start, rank, csr_src, E);

  // K5: aggregate
  gat_agg<<<(N + 3) / 4, 256, 0, stream>>>(XHb, a_src, a_dst, row_start, deg,
                                           csr_src, bias, out, N);
}

// Round 15
// 148.091 us; speedup vs baseline: 1.0095x; 1.0095x over previous
//
#include <hip/hip_runtime.h>

#define NEG_SLOPE 0.2f
#define LRELU(x) ((x) > 0.0f ? (x) : NEG_SLOPE * (x))

typedef short short8 __attribute__((ext_vector_type(8)));
typedef unsigned short ushort8 __attribute__((ext_vector_type(8)));
typedef float f32x4v __attribute__((ext_vector_type(4)));

__device__ __forceinline__ unsigned short f2bf(float f) {
  unsigned int u = __float_as_uint(f);
  unsigned int r = (u + 0x7FFFu + ((u >> 16) & 1u)) >> 16;
  return (unsigned short)r;
}

__device__ __forceinline__ float bf2f(unsigned short u) {
  return __uint_as_float(((unsigned int)u) << 16);
}

__device__ __forceinline__ unsigned int cvt_pk_bf16(float lo, float hi) {
  unsigned int r;
  asm("v_cvt_pk_bf16_f32 %0, %1, %2" : "=v"(r) : "v"(lo), "v"(hi));
  return r;
}

__device__ __forceinline__ void gload_lds16(const void* g, void* l) {
  __builtin_amdgcn_global_load_lds(
      (const __attribute__((address_space(1))) unsigned int*)g,
      (__attribute__((address_space(3))) unsigned int*)l, 16, 0, 0);
}

// block-range split constants
#define CBC 448    // count blocks (fused_pre)
#define CBW 64     // convert_wt blocks (fused_pre)
#define CBF 1024   // fill blocks (fused_main, after gemm blocks)

// ---- K1: count+rank || convert_wt -------------------------------------------
__global__ __launch_bounds__(256) void fused_pre(
    const float* __restrict__ W, unsigned short* __restrict__ Wtb,
    const int* __restrict__ ei, int* __restrict__ deg,
    int* __restrict__ rank, int E) {
  int b = blockIdx.x;
  int tid = threadIdx.x;
  if (b < CBC) {
    for (int e = b * 256 + tid; e < E; e += CBC * 256)
      rank[e] = atomicAdd(&deg[ei[E + e]], 1);
  } else {
    int bb = b - CBC;
    for (int idx = bb * 256 + tid; idx < 256 * 256; idx += CBW * 256) {
      int n = idx >> 8, k = idx & 255;
      Wtb[n * 256 + k] = f2bf(W[k * 256 + n]);
    }
  }
}

// ---- K2: single-kernel scan, arrival-order region allocation ----------------
// row_start NOT globally monotone — fill uses row_start[d]+rank[e], gat_agg
// uses end = start + deg[d]. gtotal pre-zeroed by the memset.
__global__ __launch_bounds__(1024) void scan_alloc(const int* __restrict__ deg,
                                                   int* __restrict__ row_start,
                                                   int* __restrict__ gtotal, int N) {
  __shared__ int buf[1024];
  __shared__ int s_off;
  int i = blockIdx.x * 1024 + (int)threadIdx.x;
  int v = (i < N) ? deg[i] : 0;
  buf[threadIdx.x] = v;
  __syncthreads();
  int run = v;
  for (int off = 1; off < 1024; off <<= 1) {
    int t = ((int)threadIdx.x >= off) ? buf[threadIdx.x - off] : 0;
    __syncthreads();
    run += t;
    buf[threadIdx.x] = run;
    __syncthreads();
  }
  if (threadIdx.x == 1023) s_off = atomicAdd(gtotal, run);
  __syncthreads();
  if (i < N) row_start[i] = s_off + run - v;
}

// ---- K3: barrier-free MFMA GEMM (B fully LDS-resident) || atomic-free fill --
// B panel (128 n-rows x 256 K, 64KB bf16) staged ONCE via gload_lds with
// pre-swizzled global source (XOR swz spreads 512B-stride rows across banks),
// one barrier, then the K-loop has NO barriers: A-frags per-lane from f32 x
// (+ cvt_pk), B-frags from resident LDS. Waves: 32 rows x 128 cols (acc[2][8]).
// XCD-paired mapping (m-block count % 8 == 0 via Mp padded to 1024 rows).
__global__ __launch_bounds__(256) void fused_main(
    const float* __restrict__ Xf, const unsigned short* __restrict__ Wtb,
    const float* __restrict__ attS, const float* __restrict__ attD,
    unsigned short* __restrict__ XHb, float* __restrict__ a_src,
    float* __restrict__ a_dst,
    const int* __restrict__ ei, const int* __restrict__ row_start,
    const int* __restrict__ rank, int* __restrict__ csr_src,
    int nGemm, int E, int N) {
  __shared__ unsigned short lB[128 * 256];  // 64KB [n][k] bf16, swizzled rows
  const int bid = blockIdx.x;
  const int tid = threadIdx.x;

  if (bid >= nGemm) {
    // ---------------- fill (atomic-free) ----------------
    int bb = bid - nGemm;
    for (int e = bb * 256 + tid; e < E; e += CBF * 256)
      csr_src[row_start[ei[E + e]] + rank[e]] = ei[e];
    return;
  }

  // ---------------- gemm ----------------
  const int gb = bid;
  const int lane = tid & 63;
  const int wave = tid >> 6;
  const int m0 = ((gb >> 4) * 8 + (gb & 7)) * 128;
  const int n0 = ((gb >> 3) & 1) * 128;
  const int lr = lane & 15;
  const int hq = lane >> 4;

  char* lBc = (char*)&lB[0];
  const char* WtC = (const char*)Wtb;

  // B staging: 16 issues x 4KB; LDS linear, global pre-swizzled so that
  // LDS[row][c] = Wtb[n0+row][c ^ ((row&7)<<4)]  (bytes within 512B row)
#pragma unroll
  for (int is = 0; is < 16; ++is) {
    int off = is * 4096 + wave * 1024 + lane * 16;
    int row = off >> 9;
    int within = off & 511;
    int g = (off & ~511) | (within ^ ((row & 7) << 4));
    gload_lds16(WtC + (size_t)n0 * 512 + g, lBc + is * 4096 + wave * 1024);
  }

  f32x4v acc[2][8];
#pragma unroll
  for (int i = 0; i < 2; ++i)
#pragma unroll
    for (int j = 0; j < 8; ++j) acc[i][j] = (f32x4v)(0.0f);

  // A per-lane rows (this wave owns rows m0 + wave*32 .. +31)
  const int r0 = min(m0 + wave * 32 + lr, N - 1);
  const int r1 = min(m0 + wave * 32 + 16 + lr, N - 1);
  const float* ap0 = Xf + (size_t)r0 * 256 + hq * 8;
  const float* ap1 = Xf + (size_t)r1 * 256 + hq * 8;
  const int sw = (lr & 7) << 4;

  __syncthreads();  // B resident from here on; no further barriers

#pragma unroll
  for (int kk = 0; kk < 8; ++kk) {
    const int k0 = kk * 32;
    short8 a[2], b[8];
    {
      float4 f00 = *reinterpret_cast<const float4*>(ap0 + k0);
      float4 f01 = *reinterpret_cast<const float4*>(ap0 + k0 + 4);
      float4 f10 = *reinterpret_cast<const float4*>(ap1 + k0);
      float4 f11 = *reinterpret_cast<const float4*>(ap1 + k0 + 4);
      union { unsigned int u[4]; short8 s; } ua0, ua1;
      ua0.u[0] = cvt_pk_bf16(f00.x, f00.y);
      ua0.u[1] = cvt_pk_bf16(f00.z, f00.w);
      ua0.u[2] = cvt_pk_bf16(f01.x, f01.y);
      ua0.u[3] = cvt_pk_bf16(f01.z, f01.w);
      ua1.u[0] = cvt_pk_bf16(f10.x, f10.y);
      ua1.u[1] = cvt_pk_bf16(f10.z, f10.w);
      ua1.u[2] = cvt_pk_bf16(f11.x, f11.y);
      ua1.u[3] = cvt_pk_bf16(f11.z, f11.w);
      a[0] = ua0.s;
      a[1] = ua1.s;
    }
    const int cbyte = (k0 * 2 + hq * 16) ^ sw;
#pragma unroll
    for (int j = 0; j < 8; ++j)
      b[j] = *reinterpret_cast<const short8*>(lBc + (j * 16 + lr) * 512 + cbyte);
#pragma unroll
    for (int i = 0; i < 2; ++i)
#pragma unroll
      for (int j = 0; j < 8; ++j)
        acc[i][j] = __builtin_amdgcn_mfma_f32_16x16x32_bf16(a[i], b[j], acc[i][j], 0, 0, 0);
  }

  // ---- epilogue: fused attention dots (2 heads per wave) + bf16 store ----
  const int h0 = n0 >> 6;  // cols n0..n0+127 span heads h0, h0+1
  float ws_[8], wd_[8];
#pragma unroll
  for (int j = 0; j < 8; ++j) {
    ws_[j] = attS[(h0 + (j >> 2)) * 64 + (j & 3) * 16 + lr];
    wd_[j] = attD[(h0 + (j >> 2)) * 64 + (j & 3) * 16 + lr];
  }
  const int rbase = m0 + wave * 32 + hq * 4;

#pragma unroll
  for (int i = 0; i < 2; ++i) {
#pragma unroll
    for (int r = 0; r < 4; ++r) {
      float ps0 = 0.f, pd0 = 0.f, ps1 = 0.f, pd1 = 0.f;
#pragma unroll
      for (int j = 0; j < 4; ++j) {
        ps0 += acc[i][j][r] * ws_[j];
        pd0 += acc[i][j][r] * wd_[j];
        ps1 += acc[i][j + 4][r] * ws_[j + 4];
        pd1 += acc[i][j + 4][r] * wd_[j + 4];
      }
#pragma unroll
      for (int off = 1; off < 16; off <<= 1) {
        ps0 += __shfl_xor(ps0, off, 64);
        pd0 += __shfl_xor(pd0, off, 64);
        ps1 += __shfl_xor(ps1, off, 64);
        pd1 += __shfl_xor(pd1, off, 64);
      }
      int row = rbase + i * 16 + r;
      if (lr == 0 && row < N) {
        a_src[row * 4 + h0] = ps0;
        a_dst[row * 4 + h0] = pd0;
        a_src[row * 4 + h0 + 1] = ps1;
        a_dst[row * 4 + h0 + 1] = pd1;
      }
    }
  }

#pragma unroll
  for (int i = 0; i < 2; ++i)
#pragma unroll
    for (int j = 0; j < 8; ++j) {
      int col = n0 + j * 16 + lr;
#pragma unroll
      for (int r = 0; r < 4; ++r) {
        int row = rbase + i * 16 + r;
        XHb[(size_t)row * 256 + col] = f2bf(acc[i][j][r]);
      }
    }
}

// ---- K4: fused softmax + aggregation, half-wave row gathers -----------------
// end = start + deg[node] (row_start is per-node region base, not monotone)
__global__ __launch_bounds__(256) void gat_agg(
    const unsigned short* __restrict__ XHb, const float* __restrict__ a_src,
    const float* __restrict__ a_dst, const int* __restrict__ row_start,
    const int* __restrict__ deg, const int* __restrict__ csr_src,
    const float* __restrict__ bias, float* __restrict__ out, int N) {
  int wid = threadIdx.x >> 6;
  int lane = threadIdx.x & 63;
  int node = blockIdx.x * 4 + wid;
  if (node >= N) return;

  const int half = lane >> 5;
  const int l5 = lane & 31;
  const int h = l5 >> 3;
  const int c = l5 << 3;
  const unsigned short* __restrict__ xrow = XHb + c;

  float ad_h = a_dst[node * 4 + h];
  float as_h = a_src[node * 4 + h];

  int start = row_start[node];
  int end = start + deg[node];

  float acc[8];
  float sw = 0.f;
  if (half == 0) {
    float wself = __expf(LRELU(as_h + ad_h));
    ushort8 sv = *reinterpret_cast<const ushort8*>(xrow + (size_t)node * 256);
#pragma unroll
    for (int k = 0; k < 8; ++k) acc[k] = wself * bf2f(sv[k]);
    sw = wself;
  } else {
#pragma unroll
    for (int k = 0; k < 8; ++k) acc[k] = 0.f;
  }

  int p = start;
  for (; p + 8 <= end; p += 8) {
    int s0 = csr_src[p + half];
    int s1 = csr_src[p + 2 + half];
    int s2 = csr_src[p + 4 + half];
    int s3 = csr_src[p + 6 + half];
    float a0 = a_src[s0 * 4 + h] + ad_h;
    float a1 = a_src[s1 * 4 + h] + ad_h;
    float a2 = a_src[s2 * 4 + h] + ad_h;
    float a3 = a_src[s3 * 4 + h] + ad_h;
    ushort8 u0 = *reinterpret_cast<const ushort8*>(xrow + (size_t)s0 * 256);
    ushort8 u1 = *reinterpret_cast<const ushort8*>(xrow + (size_t)s1 * 256);
    ushort8 u2 = *reinterpret_cast<const ushort8*>(xrow + (size_t)s2 * 256);
    ushort8 u3 = *reinterpret_cast<const ushort8*>(xrow + (size_t)s3 * 256);
    float w0 = __expf(LRELU(a0));
    float w1 = __expf(LRELU(a1));
    float w2 = __expf(LRELU(a2));
    float w3 = __expf(LRELU(a3));
#pragma unroll
    for (int k = 0; k < 8; ++k) {
      acc[k] += w0 * bf2f(u0[k]);
      acc[k] += w1 * bf2f(u1[k]);
      acc[k] += w2 * bf2f(u2[k]);
      acc[k] += w3 * bf2f(u3[k]);
    }
    sw += (w0 + w1) + (w2 + w3);
  }
#pragma unroll
  for (int k = 0; k < 4; ++k) {
    int idx = p + 2 * k + half;
    if (idx < end) {
      int s = csr_src[idx];
      float aa = a_src[s * 4 + h] + ad_h;
      ushort8 u = *reinterpret_cast<const ushort8*>(xrow + (size_t)s * 256);
      float ww = __expf(LRELU(aa));
#pragma unroll
      for (int q = 0; q < 8; ++q) acc[q] += ww * bf2f(u[q]);
      sw += ww;
    }
  }

  sw += __shfl_xor(sw, 32, 64);
#pragma unroll
  for (int k = 0; k < 8; ++k) acc[k] += __shfl_xor(acc[k], 32, 64);

  if (half == 0) {
    float inv = 1.0f / sw;
    float4 b0 = *reinterpret_cast<const float4*>(bias + c);
    float4 b1 = *reinterpret_cast<const float4*>(bias + c + 4);
    float4 o0, o1;
    o0.x = acc[0] * inv + b0.x; o0.y = acc[1] * inv + b0.y;
    o0.z = acc[2] * inv + b0.z; o0.w = acc[3] * inv + b0.w;
    o1.x = acc[4] * inv + b1.x; o1.y = acc[5] * inv + b1.y;
    o1.z = acc[6] * inv + b1.z; o1.w = acc[7] * inv + b1.w;
    *reinterpret_cast<float4*>(out + (size_t)node * 256 + c) = o0;
    *reinterpret_cast<float4*>(out + (size_t)node * 256 + c + 4) = o1;
  }
}

extern "C" void kernel_launch(void* const* d_in, const int* in_sizes, int n_in,
                              void* d_out, int out_size, void* d_ws, size_t ws_size,
                              hipStream_t stream) {
  const float* x    = (const float*)d_in[0];
  const int*   ei   = (const int*)d_in[1];
  const float* Wm   = (const float*)d_in[2];
  const float* attS = (const float*)d_in[3];
  const float* attD = (const float*)d_in[4];
  const float* bias = (const float*)d_in[5];
  float* out = (float*)d_out;

  const int N = in_sizes[0] / 256;
  const int E = in_sizes[1] / 2;
  // m-block count must be a multiple of 8 for the XCD-paired gemm mapping
  const int Mp = (N + 1023) / 1024 * 1024;
  const int nb = (N + 1023) / 1024;

  char* w = (char*)d_ws;
  unsigned short* XHb = (unsigned short*)w;  w += (size_t)Mp * 256 * 2;
  unsigned short* Wtb = (unsigned short*)w;  w += (size_t)256 * 256 * 2;
  float* a_src = (float*)w;                  w += (size_t)N * 4 * 4;
  float* a_dst = (float*)w;                  w += (size_t)N * 4 * 4;
  int* deg = (int*)w;                        w += (size_t)N * 4;
  int* gtotal = (int*)w;                     w += 256;   // adjacent to deg (one memset)
  int* rank = (int*)w;                       w += (size_t)E * 4;
  int* row_start = (int*)w;                  w += ((size_t)(N + 1) * 4 + 255) / 256 * 256;
  int* csr_src = (int*)w;                    w += (size_t)E * 4;

  // zero deg + gtotal in one memset
  hipMemsetAsync(deg, 0, (size_t)N * 4 + 256, stream);

  // count (stores per-edge rank) || convert W
  fused_pre<<<CBC + CBW, 256, 0, stream>>>(Wm, Wtb, ei, deg, rank, E);

  // single-kernel scan (arrival-order region allocation)
  scan_alloc<<<nb, 1024, 0, stream>>>(deg, row_start, gtotal, N);

  // barrier-free GEMM || atomic-free fill
  const int nGemm = 2 * (Mp / 128);
  fused_main<<<nGemm + CBF, 256, 0, stream>>>(x, Wtb, attS, attD, XHb, a_src, a_dst,
                                              ei, row_start, rank, csr_src,
                                              nGemm, E, N);

  gat_agg<<<(N + 3) / 4, 256, 0, stream>>>(XHb, a_src, a_dst, row_start, deg,
                                           csr_src, bias, out, N);
}

// Round 16
// 143.181 us; speedup vs baseline: 1.0442x; 1.0343x over previous
//
#include <hip/hip_runtime.h>

#define NEG_SLOPE 0.2f
#define LRELU(x) ((x) > 0.0f ? (x) : NEG_SLOPE * (x))

typedef short short8 __attribute__((ext_vector_type(8)));
typedef unsigned short ushort8 __attribute__((ext_vector_type(8)));
typedef float f32x4v __attribute__((ext_vector_type(4)));

__device__ __forceinline__ unsigned short f2bf(float f) {
  unsigned int u = __float_as_uint(f);
  unsigned int r = (u + 0x7FFFu + ((u >> 16) & 1u)) >> 16;
  return (unsigned short)r;
}

__device__ __forceinline__ float bf2f(unsigned short u) {
  return __uint_as_float(((unsigned int)u) << 16);
}

__device__ __forceinline__ unsigned int cvt_pk_bf16(float lo, float hi) {
  unsigned int r;
  asm("v_cvt_pk_bf16_f32 %0, %1, %2" : "=v"(r) : "v"(lo), "v"(hi));
  return r;
}

__device__ __forceinline__ void gload_lds16(const void* g, void* l) {
  __builtin_amdgcn_global_load_lds(
      (const __attribute__((address_space(1))) unsigned int*)g,
      (__attribute__((address_space(3))) unsigned int*)l, 16, 0, 0);
}

// block-range split constants
#define CBC 448    // count blocks (fused_cg, AFTER gemm blocks - backfill)
#define CBF 1024   // fill blocks

// ---- K1: convert_wt || zero deg || zero gtotal ------------------------------
__global__ __launch_bounds__(256) void prep_kernel(
    const float* __restrict__ W, unsigned short* __restrict__ Wtb,
    int* __restrict__ deg, int* __restrict__ gtotal, int N) {
  int t = blockIdx.x * 256 + threadIdx.x;  // 0..16383
  for (int idx = t; idx < 256 * 256; idx += 64 * 256) {
    int n = idx >> 8, k = idx & 255;
    Wtb[n * 256 + k] = f2bf(W[k * 256 + n]);
  }
  for (int i = t; i < N; i += 64 * 256) deg[i] = 0;
  if (t == 0) *gtotal = 0;
}

// ---- K2: MFMA GEMM (blocks [0,nGemm), FIRST) || count+rank (backfill) -------
// All 784+448 blocks co-resident (16KB LDS -> 5 blocks/CU VGPR cap): count's
// latency-bound atomic waves soak issue slots idle during gemm's MFMA waves.
// gemm: 128x128 tile, reg-staged f32 A -> cvt_pk -> bf16 LDS; B via gload_lds;
// XCD-paired mapping (m-block count % 8 == 0 via Mp padded to 1024 rows).
// count: rank[e] = old deg value (coalesced store) -> fill needs NO atomics.
__global__ __launch_bounds__(256) void fused_cg(
    const float* __restrict__ Xf, const unsigned short* __restrict__ Wtb,
    const float* __restrict__ attS, const float* __restrict__ attD,
    unsigned short* __restrict__ XHb, float* __restrict__ a_src,
    float* __restrict__ a_dst,
    const int* __restrict__ ei, int* __restrict__ deg,
    int* __restrict__ rank, int nGemm, int E, int N) {
  __shared__ unsigned short lA[128 * 32];  // 8KB [row][k], 64B/row
  __shared__ unsigned short lB[128 * 32];  // 8KB [n][k],   64B/row
  const int bid = blockIdx.x;
  const int tid = threadIdx.x;

  if (bid >= nGemm) {
    // ---------------- count + rank (backfills free wave slots) ----------------
    int bb = bid - nGemm;
    for (int e = bb * 256 + tid; e < E; e += CBC * 256)
      rank[e] = atomicAdd(&deg[ei[E + e]], 1);
    return;
  }

  // ---------------- gemm ----------------
  const int gb = bid;
  const int lane = tid & 63;
  const int wave = tid >> 6;
  const int m0 = ((gb >> 4) * 8 + (gb & 7)) * 128;
  const int n0 = ((gb >> 3) & 1) * 128;
  const int wr = (wave >> 1) * 64;
  const int wc = (wave & 1) * 64;

  f32x4v acc[4][4];
#pragma unroll
  for (int i = 0; i < 4; ++i)
#pragma unroll
    for (int j = 0; j < 4; ++j) acc[i][j] = (f32x4v)(0.0f);

  const int srow = tid >> 2;
  const int skb = (tid & 3) * 16;
  const float* ap0 = Xf + (size_t)min(m0 + (tid >> 2), N - 1) * 256 + (tid & 3) * 8;
  const float* ap1 = Xf + (size_t)min(m0 + 64 + (tid >> 2), N - 1) * 256 + (tid & 3) * 8;

  const char* WtC = (const char*)Wtb;
  char* lAc = (char*)&lA[0];
  char* lBc = (char*)&lB[0];
  const int ldsB0 = wave * 1024;
  const int lr = lane & 15;
  const int hq = lane >> 4;
  const int kq = hq * 16;

  float4 c0 = *reinterpret_cast<const float4*>(ap0);
  float4 c1 = *reinterpret_cast<const float4*>(ap0 + 4);
  float4 c2 = *reinterpret_cast<const float4*>(ap1);
  float4 c3 = *reinterpret_cast<const float4*>(ap1 + 4);

#pragma unroll
  for (int kk = 0; kk < 8; ++kk) {
    const int k0 = kk * 32;
    gload_lds16(WtC + (size_t)(n0 + srow) * 512 + (size_t)k0 * 2 + skb, lBc + ldsB0);
    gload_lds16(WtC + (size_t)(n0 + srow + 64) * 512 + (size_t)k0 * 2 + skb,
                lBc + ldsB0 + 4096);
    {
      uint4 w0, w1;
      w0.x = cvt_pk_bf16(c0.x, c0.y); w0.y = cvt_pk_bf16(c0.z, c0.w);
      w0.z = cvt_pk_bf16(c1.x, c1.y); w0.w = cvt_pk_bf16(c1.z, c1.w);
      w1.x = cvt_pk_bf16(c2.x, c2.y); w1.y = cvt_pk_bf16(c2.z, c2.w);
      w1.z = cvt_pk_bf16(c3.x, c3.y); w1.w = cvt_pk_bf16(c3.z, c3.w);
      *reinterpret_cast<uint4*>(lAc + tid * 16) = w0;          // rows 0..63
      *reinterpret_cast<uint4*>(lAc + 4096 + tid * 16) = w1;   // rows 64..127
    }
    if (kk < 7) {
      c0 = *reinterpret_cast<const float4*>(ap0 + k0 + 32);
      c1 = *reinterpret_cast<const float4*>(ap0 + k0 + 36);
      c2 = *reinterpret_cast<const float4*>(ap1 + k0 + 32);
      c3 = *reinterpret_cast<const float4*>(ap1 + k0 + 36);
    }
    __syncthreads();

    short8 a[4], b[4];
#pragma unroll
    for (int i = 0; i < 4; ++i)
      a[i] = *reinterpret_cast<const short8*>(lAc + (wr + i * 16 + lr) * 64 + kq);
#pragma unroll
    for (int j = 0; j < 4; ++j)
      b[j] = *reinterpret_cast<const short8*>(lBc + (wc + j * 16 + lr) * 64 + kq);
#pragma unroll
    for (int i = 0; i < 4; ++i)
#pragma unroll
      for (int j = 0; j < 4; ++j)
        acc[i][j] = __builtin_amdgcn_mfma_f32_16x16x32_bf16(a[i], b[j], acc[i][j], 0, 0, 0);
    __syncthreads();
  }

  // ---- epilogue: fused attention dots + bf16 store ----
  const int h = (n0 + wc) >> 6;
  float ws_[4], wd_[4];
#pragma unroll
  for (int j = 0; j < 4; ++j) {
    ws_[j] = attS[h * 64 + j * 16 + lr];
    wd_[j] = attD[h * 64 + j * 16 + lr];
  }
  const int rbase = m0 + wr + hq * 4;

#pragma unroll
  for (int i = 0; i < 4; ++i) {
#pragma unroll
    for (int r = 0; r < 4; ++r) {
      float ps = 0.f, pd = 0.f;
#pragma unroll
      for (int j = 0; j < 4; ++j) {
        ps += acc[i][j][r] * ws_[j];
        pd += acc[i][j][r] * wd_[j];
      }
#pragma unroll
      for (int off = 1; off < 16; off <<= 1) {
        ps += __shfl_xor(ps, off, 64);
        pd += __shfl_xor(pd, off, 64);
      }
      int row = rbase + i * 16 + r;
      if (lr == 0 && row < N) {
        a_src[row * 4 + h] = ps;
        a_dst[row * 4 + h] = pd;
      }
    }
  }

#pragma unroll
  for (int i = 0; i < 4; ++i)
#pragma unroll
    for (int j = 0; j < 4; ++j) {
      int col = n0 + wc + j * 16 + lr;
#pragma unroll
      for (int r = 0; r < 4; ++r)
        XHb[(size_t)(rbase + i * 16 + r) * 256 + col] = f2bf(acc[i][j][r]);
    }
}

// ---- K3: single-kernel scan, arrival-order region allocation ----------------
__global__ __launch_bounds__(1024) void scan_alloc(const int* __restrict__ deg,
                                                   int* __restrict__ row_start,
                                                   int* __restrict__ gtotal, int N) {
  __shared__ int buf[1024];
  __shared__ int s_off;
  int i = blockIdx.x * 1024 + (int)threadIdx.x;
  int v = (i < N) ? deg[i] : 0;
  buf[threadIdx.x] = v;
  __syncthreads();
  int run = v;
  for (int off = 1; off < 1024; off <<= 1) {
    int t = ((int)threadIdx.x >= off) ? buf[threadIdx.x - off] : 0;
    __syncthreads();
    run += t;
    buf[threadIdx.x] = run;
    __syncthreads();
  }
  if (threadIdx.x == 1023) s_off = atomicAdd(gtotal, run);
  __syncthreads();
  if (i < N) row_start[i] = s_off + run - v;
}

// ---- K4: CSR fill, atomic-free ----------------------------------------------
__global__ __launch_bounds__(256) void fill_kernel(
    const int* __restrict__ ei, const int* __restrict__ row_start,
    const int* __restrict__ rank, int* __restrict__ csr_src, int E) {
  for (int e = blockIdx.x * 256 + threadIdx.x; e < E; e += CBF * 256)
    csr_src[row_start[ei[E + e]] + rank[e]] = ei[e];
}

// ---- K5: fused softmax + aggregation, half-wave row gathers -----------------
__global__ __launch_bounds__(256) void gat_agg(
    const unsigned short* __restrict__ XHb, const float* __restrict__ a_src,
    const float* __restrict__ a_dst, const int* __restrict__ row_start,
    const int* __restrict__ deg, const int* __restrict__ csr_src,
    const float* __restrict__ bias, float* __restrict__ out, int N) {
  int wid = threadIdx.x >> 6;
  int lane = threadIdx.x & 63;
  int node = blockIdx.x * 4 + wid;
  if (node >= N) return;

  const int half = lane >> 5;
  const int l5 = lane & 31;
  const int h = l5 >> 3;
  const int c = l5 << 3;
  const unsigned short* __restrict__ xrow = XHb + c;

  float ad_h = a_dst[node * 4 + h];
  float as_h = a_src[node * 4 + h];

  int start = row_start[node];
  int end = start + deg[node];

  float acc[8];
  float sw = 0.f;
  if (half == 0) {
    float wself = __expf(LRELU(as_h + ad_h));
    ushort8 sv = *reinterpret_cast<const ushort8*>(xrow + (size_t)node * 256);
#pragma unroll
    for (int k = 0; k < 8; ++k) acc[k] = wself * bf2f(sv[k]);
    sw = wself;
  } else {
#pragma unroll
    for (int k = 0; k < 8; ++k) acc[k] = 0.f;
  }

  int p = start;
  for (; p + 8 <= end; p += 8) {
    int s0 = csr_src[p + half];
    int s1 = csr_src[p + 2 + half];
    int s2 = csr_src[p + 4 + half];
    int s3 = csr_src[p + 6 + half];
    float a0 = a_src[s0 * 4 + h] + ad_h;
    float a1 = a_src[s1 * 4 + h] + ad_h;
    float a2 = a_src[s2 * 4 + h] + ad_h;
    float a3 = a_src[s3 * 4 + h] + ad_h;
    ushort8 u0 = *reinterpret_cast<const ushort8*>(xrow + (size_t)s0 * 256);
    ushort8 u1 = *reinterpret_cast<const ushort8*>(xrow + (size_t)s1 * 256);
    ushort8 u2 = *reinterpret_cast<const ushort8*>(xrow + (size_t)s2 * 256);
    ushort8 u3 = *reinterpret_cast<const ushort8*>(xrow + (size_t)s3 * 256);
    float w0 = __expf(LRELU(a0));
    float w1 = __expf(LRELU(a1));
    float w2 = __expf(LRELU(a2));
    float w3 = __expf(LRELU(a3));
#pragma unroll
    for (int k = 0; k < 8; ++k) {
      acc[k] += w0 * bf2f(u0[k]);
      acc[k] += w1 * bf2f(u1[k]);
      acc[k] += w2 * bf2f(u2[k]);
      acc[k] += w3 * bf2f(u3[k]);
    }
    sw += (w0 + w1) + (w2 + w3);
  }
#pragma unroll
  for (int k = 0; k < 4; ++k) {
    int idx = p + 2 * k + half;
    if (idx < end) {
      int s = csr_src[idx];
      float aa = a_src[s * 4 + h] + ad_h;
      ushort8 u = *reinterpret_cast<const ushort8*>(xrow + (size_t)s * 256);
      float ww = __expf(LRELU(aa));
#pragma unroll
      for (int q = 0; q < 8; ++q) acc[q] += ww * bf2f(u[q]);
      sw += ww;
    }
  }

  sw += __shfl_xor(sw, 32, 64);
#pragma unroll
  for (int k = 0; k < 8; ++k) acc[k] += __shfl_xor(acc[k], 32, 64);

  if (half == 0) {
    float inv = 1.0f / sw;
    float4 b0 = *reinterpret_cast<const float4*>(bias + c);
    float4 b1 = *reinterpret_cast<const float4*>(bias + c + 4);
    float4 o0, o1;
    o0.x = acc[0] * inv + b0.x; o0.y = acc[1] * inv + b0.y;
    o0.z = acc[2] * inv + b0.z; o0.w = acc[3] * inv + b0.w;
    o1.x = acc[4] * inv + b1.x; o1.y = acc[5] * inv + b1.y;
    o1.z = acc[6] * inv + b1.z; o1.w = acc[7] * inv + b1.w;
    *reinterpret_cast<float4*>(out + (size_t)node * 256 + c) = o0;
    *reinterpret_cast<float4*>(out + (size_t)node * 256 + c + 4) = o1;
  }
}

extern "C" void kernel_launch(void* const* d_in, const int* in_sizes, int n_in,
                              void* d_out, int out_size, void* d_ws, size_t ws_size,
                              hipStream_t stream) {
  const float* x    = (const float*)d_in[0];
  const int*   ei   = (const int*)d_in[1];
  const float* Wm   = (const float*)d_in[2];
  const float* attS = (const float*)d_in[3];
  const float* attD = (const float*)d_in[4];
  const float* bias = (const float*)d_in[5];
  float* out = (float*)d_out;

  const int N = in_sizes[0] / 256;
  const int E = in_sizes[1] / 2;
  // m-block count must be a multiple of 8 for the XCD-paired gemm mapping
  const int Mp = (N + 1023) / 1024 * 1024;
  const int nb = (N + 1023) / 1024;

  char* w = (char*)d_ws;
  unsigned short* XHb = (unsigned short*)w;  w += (size_t)Mp * 256 * 2;
  unsigned short* Wtb = (unsigned short*)w;  w += (size_t)256 * 256 * 2;
  float* a_src = (float*)w;                  w += (size_t)N * 4 * 4;
  float* a_dst = (float*)w;                  w += (size_t)N * 4 * 4;
  int* deg = (int*)w;                        w += (size_t)N * 4;
  int* gtotal = (int*)w;                     w += 256;
  int* rank = (int*)w;                       w += (size_t)E * 4;
  int* row_start = (int*)w;                  w += ((size_t)(N + 1) * 4 + 255) / 256 * 256;
  int* csr_src = (int*)w;                    w += (size_t)E * 4;

  // K1: convert W || zero deg || zero gtotal (memset dispatch absorbed)
  prep_kernel<<<64, 256, 0, stream>>>(Wm, Wtb, deg, gtotal, N);

  // K2: gemm (first) || count+rank (backfill) — all blocks co-resident
  const int nGemm = 2 * (Mp / 128);
  fused_cg<<<nGemm + CBC, 256, 0, stream>>>(x, Wtb, attS, attD, XHb, a_src, a_dst,
                                            ei, deg, rank, nGemm, E, N);

  // K3: single-kernel scan (arrival-order region allocation)
  scan_alloc<<<nb, 1024, 0, stream>>>(deg, row_start, gtotal, N);

  // K4: atomic-free fill
  fill_kernel<<<CBF, 256, 0, stream>>>(ei, row_start, rank, csr_src, E);

  // K5: aggregate
  gat_agg<<<(N + 3) / 4, 256, 0, stream>>>(XHb, a_src, a_dst, row_start, deg,
                                           csr_src, bias, out, N);
}